// Round 1
// 178.400 us; speedup vs baseline: 1.0109x; 1.0109x over previous
//
#include <hip/hip_runtime.h>

// DeepLinearNet: out = x @ (W_0^T ... W_63^T), x:(8388608,3) fp32, W:(64,3,3) fp32.
// R6: test the "LLC write-allocation is the ~3.2 TB/s wall" theory.
//   Loads + in-block fp64 fold unchanged from R5 (reads provably benefit from
//   Infinity Cache: FETCH=50MB of a 96MiB input). Stores now go through a 12KB
//   LDS repack -> dense full-64B-line global_store_dwordx4 with nt
//   (__builtin_nontemporal_store), bypassing L2/LLC allocation on the write
//   stream. R3's nt regression (WRITE 100->136MB) was partial-line RMW from the
//   48B-lane-stride stores; dense lines remove that confound.
// Discriminators: WRITE_SIZE must stay ~98.3e3 KB (no RMW inflation);
//   LDS_BANK_CONFLICT ~0; theory-true => dur 64 -> ~45us, theory-false => ~64.
// History: R1 strided(60us) == R2 LDS-coalesced(60) == R4 persistent+prefetch
//   (61-63); R3 nt strided stores regressed (78, WRITE inflated); R5 fused
//   fold (this base) 63-66us.

#define DEPTH 64
#define BLOCK 256
#define GRID  2048
#define GPT   4               // row-group units (3 float4s) per thread

typedef float vf4 __attribute__((ext_vector_type(4)));

__global__ __launch_bounds__(BLOCK) void deep_linear(
        const float* __restrict__ W, const vf4* __restrict__ x4,
        vf4* __restrict__ o4) {
    __shared__ double M[DEPTH][9];
    __shared__ float Ps[9];
    __shared__ vf4 S[3 * BLOCK];          // 12 KB dense-store staging
    const int tid = threadIdx.x;
    const int base = blockIdx.x * (BLOCK * GPT);

    // ---- 1. issue all 12 independent data loads up front ----
    vf4 A[GPT][3];
    #pragma unroll
    for (int k = 0; k < GPT; ++k) {
        const vf4* p = x4 + 3 * (base + k * BLOCK + tid);
        A[k][0] = p[0];
        A[k][1] = p[1];
        A[k][2] = p[2];
    }

    // ---- 2. in-block fold: P = W_0^T W_1^T ... W_63^T (fp64 tree) ----
    if (tid < DEPTH) {
        const float* Wl = W + tid * 9;
        #pragma unroll
        for (int kk = 0; kk < 3; ++kk)
            #pragma unroll
            for (int j = 0; j < 3; ++j)
                M[tid][kk * 3 + j] = (double)Wl[j * 3 + kk];   // M_t = W_t^T
    }
    __syncthreads();
    #pragma unroll
    for (int s = 1; s < DEPTH; s <<= 1) {
        if (tid < DEPTH && (tid & (2 * s - 1)) == 0) {
            double a[9], b[9], c[9];
            #pragma unroll
            for (int i = 0; i < 9; ++i) { a[i] = M[tid][i]; b[i] = M[tid + s][i]; }
            #pragma unroll
            for (int i = 0; i < 3; ++i)
                #pragma unroll
                for (int j = 0; j < 3; ++j)
                    c[i * 3 + j] = a[i * 3 + 0] * b[0 * 3 + j]
                                 + a[i * 3 + 1] * b[1 * 3 + j]
                                 + a[i * 3 + 2] * b[2 * 3 + j];
            #pragma unroll
            for (int i = 0; i < 9; ++i) M[tid][i] = c[i];
        }
        __syncthreads();
    }
    if (tid < 9) Ps[tid] = (float)M[0][tid];   // out_j = sum_k x_k * P[k*3+j]
    __syncthreads();

    const float p00 = Ps[0], p01 = Ps[1], p02 = Ps[2];
    const float p10 = Ps[3], p11 = Ps[4], p12 = Ps[5];
    const float p20 = Ps[6], p21 = Ps[7], p22 = Ps[8];

    // ---- 3. compute -> LDS repack -> dense full-line nt stores ----
    #pragma unroll
    for (int k = 0; k < GPT; ++k) {
        const vf4 a = A[k][0], b = A[k][1], c = A[k][2];
        // rows: r0=(a0,a1,a2) r1=(a3,b0,b1) r2=(b2,b3,c0) r3=(c1,c2,c3)
        vf4 oa, ob, oc;
        oa[0] = fmaf(a[0], p00, fmaf(a[1], p10, a[2] * p20));
        oa[1] = fmaf(a[0], p01, fmaf(a[1], p11, a[2] * p21));
        oa[2] = fmaf(a[0], p02, fmaf(a[1], p12, a[2] * p22));
        oa[3] = fmaf(a[3], p00, fmaf(b[0], p10, b[1] * p20));
        ob[0] = fmaf(a[3], p01, fmaf(b[0], p11, b[1] * p21));
        ob[1] = fmaf(a[3], p02, fmaf(b[0], p12, b[1] * p22));
        ob[2] = fmaf(b[2], p00, fmaf(b[3], p10, c[0] * p20));
        ob[3] = fmaf(b[2], p01, fmaf(b[3], p11, c[0] * p21));
        oc[0] = fmaf(b[2], p02, fmaf(b[3], p12, c[0] * p22));
        oc[1] = fmaf(c[1], p00, fmaf(c[2], p10, c[3] * p20));
        oc[2] = fmaf(c[1], p01, fmaf(c[2], p11, c[3] * p21));
        oc[3] = fmaf(c[1], p02, fmaf(c[2], p12, c[3] * p22));

        if (k) __syncthreads();            // previous iteration's S reads done
        // LDS write: byte addr 48*tid -> 8 lanes span all 32 banks, conflict-free
        S[3 * tid + 0] = oa;
        S[3 * tid + 1] = ob;
        S[3 * tid + 2] = oc;
        __syncthreads();
        // dense read (byte addr 16*tid) + full-line non-temporal store:
        // 4 consecutive lanes fully cover one 64B line in one instruction
        vf4* q = o4 + 3 * (base + k * BLOCK);
        __builtin_nontemporal_store(S[tid],             q + tid);
        __builtin_nontemporal_store(S[tid + BLOCK],     q + tid + BLOCK);
        __builtin_nontemporal_store(S[tid + 2 * BLOCK], q + tid + 2 * BLOCK);
    }
}

extern "C" void kernel_launch(void* const* d_in, const int* in_sizes, int n_in,
                              void* d_out, int out_size, void* d_ws, size_t ws_size,
                              hipStream_t stream) {
    const float* x = (const float*)d_in[0];
    const float* W = (const float*)d_in[1];
    float* out = (float*)d_out;
    (void)d_ws; (void)ws_size;

    // 2048 blocks x 256 threads x 4 units x 4 rows = 8388608 rows: exact fit
    deep_linear<<<GRID, BLOCK, 0, stream>>>(W, (const vf4*)x, (vf4*)out);
}